// Round 5
// baseline (1435.551 us; speedup 1.0000x reference)
//
#include <hip/hip_runtime.h>

#define T_STEPS 2048
#define BATCH   128
#define HID     100     // LSTM hidden size
#define HP      112     // padded h: [0..99]=h, [100]=1.0 (bias), [101]=x_t, rest 0
#define NTH     256     // 4 waves; quads 0..49 active, 2 units per quad

#define LOG2E 1.44269504088896340736f

// DPP quad_perm helpers (VALU pipe, immediate ctrl)
template <int CTRL>
__device__ __forceinline__ float dpp_mov(float v) {
    int y = __builtin_amdgcn_update_dpp(0, __float_as_int(v), CTRL, 0xF, 0xF, true);
    return __int_as_float(y);
}

__global__ __launch_bounds__(NTH)
__attribute__((amdgpu_waves_per_eu(1, 1)))
void lstm_caviar_kernel(
    const float* __restrict__ x,      // [T, B, 1]
    const float* __restrict__ W_ih,   // [400, 1]
    const float* __restrict__ W_hh,   // [400, 100]
    const float* __restrict__ b_ih,   // [400]
    const float* __restrict__ b_hh,   // [400]
    const float* __restrict__ W1,     // [64, 100]
    const float* __restrict__ b1,     // [64]
    const float* __restrict__ W2,     // [1, 64]
    const float* __restrict__ b2,     // [1]
    float* __restrict__ out)          // [1]
{
    __shared__ __align__(16) float h_buf[2][HP];
    __shared__ float x_lds[T_STEPS];
    __shared__ float red_lds[64];

    const int tid = threadIdx.x;
    const int q   = tid >> 2;     // quad id: owns units 2q, 2q+1
    const int s   = tid & 3;      // k-split / gate-specialization lane
    const bool active = (q < HID / 2);

    // stage batch-0 inputs (x[t,0,0] = flat[t*BATCH]) into LDS once
    for (int t = tid; t < T_STEPS; t += NTH)
        x_lds[t] = x[t * BATCH];
    if (tid < HP) { h_buf[0][tid] = 0.0f; h_buf[1][tid] = 0.0f; }
    __syncthreads();
    if (tid == 0) {
        h_buf[0][100] = 1.0f;        // virtual element: bias multiplier
        h_buf[1][100] = 1.0f;
        h_buf[0][101] = x_lds[0];    // virtual element: x_t
    }

    // Preload weights: lane covers k = 16*m + 4*s + d (m=0..6, d=0..3) for
    // 8 dot products (4 gates x 2 units). Virtual columns: k=100 -> bias
    // (b_ih+b_hh, unscaled: only lane s=1 holds it, butterfly sums once),
    // k=101 -> W_ih (x feed). Rows pre-scaled by log2(e) (2x for gate g) so
    // activations use raw exp2:
    //   sigmoid(p) = rcp(1 + exp2(-L*p)),  tanh(p) = 2*rcp(1 + exp2(-2L*p)) - 1
    float w[2][4][28];
    #pragma unroll
    for (int u = 0; u < 2; ++u) {
        #pragma unroll
        for (int g = 0; g < 4; ++g) {
            const int unit = active ? (2 * q + u) : 0;
            const int r = g * HID + unit;
            const float Lg = (g == 2) ? (2.0f * LOG2E) : LOG2E;
            #pragma unroll
            for (int m = 0; m < 7; ++m) {
                #pragma unroll
                for (int d = 0; d < 4; ++d) {
                    const int k = 16 * m + 4 * s + d;
                    float val = 0.0f;
                    if (k < HID)       val = W_hh[r * HID + k];
                    else if (k == 100) val = b_ih[r] + b_hh[r];
                    else if (k == 101) val = W_ih[r];
                    w[u][g][4 * m + d] = active ? (Lg * val) : 0.0f;
                }
            }
        }
    }

    const bool b0     = (s & 1) != 0;
    const bool b1h    = (s & 2) != 0;
    const bool is_g   = (s == 2);
    const bool wr     = active && (s == 0);
    const bool feeder = (q == 50) && (s == 0);   // lane 200 (wave 3, off hot SIMDs)
    const int  hoff   = 4 * s;
    float cA = 0.0f, cB = 0.0f;
    __syncthreads();

    for (int t = 0; t < T_STEPS; ++t) {
        const float* hb = h_buf[t & 1] + hoff;
        float* hn = h_buf[(t + 1) & 1];

        float aA0 = 0.f, aA1 = 0.f, aA2 = 0.f, aA3 = 0.f;
        float aB0 = 0.f, aB1 = 0.f, aB2 = 0.f, aB3 = 0.f;

        #pragma unroll
        for (int m = 0; m < 7; ++m) {
            const float4 hv = *(const float4*)(hb + 16 * m);
            #define MACC(u, g, acc)                       \
                acc = fmaf(w[u][g][4*m+0], hv.x, acc);    \
                acc = fmaf(w[u][g][4*m+1], hv.y, acc);    \
                acc = fmaf(w[u][g][4*m+2], hv.z, acc);    \
                acc = fmaf(w[u][g][4*m+3], hv.w, acc);
            MACC(0, 0, aA0) MACC(0, 1, aA1) MACC(0, 2, aA2) MACC(0, 3, aA3)
            MACC(1, 0, aB0) MACC(1, 1, aB1) MACC(1, 2, aB2) MACC(1, 3, aB3)
            #undef MACC
        }

        // feed next step's x into the next buffer (idle-wave lane; before barrier)
        if (feeder) hn[101] = x_lds[(t + 1) & (T_STEPS - 1)];

        // Select-then-butterfly transpose-reduce per unit:
        // lane s ends with the FULL sum of gate s (12 VALU ops per unit).
        float p01, p01s, p23, p23s, qq, qqs;

        p01  = b0 ? aA1 : aA0;  p01s = b0 ? aA0 : aA1;
        p23  = b0 ? aA3 : aA2;  p23s = b0 ? aA2 : aA3;
        p01 += dpp_mov<0xB1>(p01s);
        p23 += dpp_mov<0xB1>(p23s);
        qq   = b1h ? p23 : p01; qqs  = b1h ? p01 : p23;
        const float totA = qq + dpp_mov<0x4E>(qqs);

        p01  = b0 ? aB1 : aB0;  p01s = b0 ? aB0 : aB1;
        p23  = b0 ? aB3 : aB2;  p23s = b0 ? aB2 : aB3;
        p01 += dpp_mov<0xB1>(p01s);
        p23 += dpp_mov<0xB1>(p23s);
        qq   = b1h ? p23 : p01; qqs  = b1h ? p01 : p23;
        const float totB = qq + dpp_mov<0x4E>(qqs);

        // lane s activates gate s for both units (i,f,o: sigmoid; g: tanh)
        const float eA   = __builtin_amdgcn_exp2f(-totA);
        const float rA   = __builtin_amdgcn_rcpf(1.0f + eA);
        const float actA = is_g ? fmaf(2.0f, rA, -1.0f) : rA;
        const float eB   = __builtin_amdgcn_exp2f(-totB);
        const float rB   = __builtin_amdgcn_rcpf(1.0f + eB);
        const float actB = is_g ? fmaf(2.0f, rB, -1.0f) : rB;

        // redistribute the four activations within the quad (DPP broadcasts)
        const float igA = dpp_mov<0x00>(actA);
        const float fgA = dpp_mov<0x55>(actA);
        const float ggA = dpp_mov<0xAA>(actA);
        const float ogA = dpp_mov<0xFF>(actA);
        const float igB = dpp_mov<0x00>(actB);
        const float fgB = dpp_mov<0x55>(actB);
        const float ggB = dpp_mov<0xAA>(actB);
        const float ogB = dpp_mov<0xFF>(actB);

        cA = fmaf(fgA, cA, igA * ggA);
        cB = fmaf(fgB, cB, igB * ggB);
        const float e2A = __builtin_amdgcn_exp2f(-2.0f * LOG2E * cA);
        const float thA = fmaf(2.0f, __builtin_amdgcn_rcpf(1.0f + e2A), -1.0f);
        const float e2B = __builtin_amdgcn_exp2f(-2.0f * LOG2E * cB);
        const float thB = fmaf(2.0f, __builtin_amdgcn_rcpf(1.0f + e2B), -1.0f);
        const float hA  = ogA * thA;
        const float hB  = ogB * thB;

        if (wr) {
            float2 hv2; hv2.x = hA; hv2.y = hB;
            *(float2*)(hn + 2 * q) = hv2;   // adjacent units -> one ds_write_b64
        }
        __syncthreads();
    }

    // head: lin = W1 @ h + b1 (64), out = W2 @ lin + b2 (scalar)
    if (tid < 64) {
        const float* rw = W1 + tid * HID;
        const float* hf = h_buf[0];   // T even -> final h in buf 0
        float a = 0.0f;
        for (int k = 0; k < HID; ++k)
            a = fmaf(rw[k], hf[k], a);
        red_lds[tid] = a + b1[tid];
    }
    __syncthreads();
    if (tid == 0) {
        float a = b2[0];
        for (int k = 0; k < 64; ++k)
            a = fmaf(W2[k], red_lds[k], a);
        out[0] = a;
    }
}

extern "C" void kernel_launch(void* const* d_in, const int* in_sizes, int n_in,
                              void* d_out, int out_size, void* d_ws, size_t ws_size,
                              hipStream_t stream) {
    lstm_caviar_kernel<<<1, NTH, 0, stream>>>(
        (const float*)d_in[0],  // input_seq
        (const float*)d_in[1],  // W_ih
        (const float*)d_in[2],  // W_hh
        (const float*)d_in[3],  // b_ih
        (const float*)d_in[4],  // b_hh
        (const float*)d_in[5],  // W1
        (const float*)d_in[6],  // b1
        (const float*)d_in[7],  // W2
        (const float*)d_in[8],  // b2
        (float*)d_out);
}

// Round 6
// 1084.923 us; speedup vs baseline: 1.3232x; 1.3232x over previous
//
#include <hip/hip_runtime.h>

#define T_STEPS 2048
#define BATCH   128
#define HID     100     // LSTM hidden size
#define HP      112     // padded hidden length (multiple of 16)
#define NTH     448     // 7 waves of 64

#define LOG2E 1.44269504088896340736f

// DPP quad_perm helpers (VALU pipe, immediate ctrl)
template <int CTRL>
__device__ __forceinline__ float dpp_mov(float v) {
    int y = __builtin_amdgcn_update_dpp(0, __float_as_int(v), CTRL, 0xF, 0xF, true);
    return __int_as_float(y);
}

__global__ __launch_bounds__(NTH)
__attribute__((amdgpu_waves_per_eu(1, 2)))
void lstm_caviar_kernel(
    const float* __restrict__ x,      // [T, B, 1]
    const float* __restrict__ W_ih,   // [400, 1]
    const float* __restrict__ W_hh,   // [400, 100]
    const float* __restrict__ b_ih,   // [400]
    const float* __restrict__ b_hh,   // [400]
    const float* __restrict__ W1,     // [64, 100]
    const float* __restrict__ b1,     // [64]
    const float* __restrict__ W2,     // [1, 64]
    const float* __restrict__ b2,     // [1]
    float* __restrict__ out)          // [1]
{
    __shared__ __align__(16) float h_buf[2][HP];
    __shared__ float x_lds[T_STEPS];
    __shared__ float red_lds[64];

    const int tid = threadIdx.x;
    const int j   = tid >> 2;     // hidden unit owned by this quad
    const int s   = tid & 3;      // k-split / gate-specialization lane
    const bool active = (j < HID);

    // stage batch-0 inputs (x[t,0,0] = flat[t*BATCH]) into LDS once
    for (int t = tid; t < T_STEPS; t += NTH)
        x_lds[t] = x[t * BATCH];
    if (tid < HP) { h_buf[0][tid] = 0.0f; h_buf[1][tid] = 0.0f; }

    // Preload W_hh fragments: lane covers k = 16*m + 4*s + d, m=0..6, d=0..3.
    // wi/bias pre-scaled by 0.25 so the 4-lane reduce sums them to exactly 1x.
    // Gate rows pre-scaled by log2(e) (2x for gate g) so activations use raw
    // exp2: sigmoid(p)=rcp(1+exp2(-L p)), tanh(p)=2*rcp(1+exp2(-2L p))-1.
    float w[4][28];
    float wi4[4], bs4[4];
    #pragma unroll
    for (int g = 0; g < 4; ++g) {
        const int gate = g * HID + (active ? j : 0);
        const float Lg = (g == 2) ? (2.0f * LOG2E) : LOG2E;
        const float* row = W_hh + gate * HID;
        #pragma unroll
        for (int m = 0; m < 7; ++m) {
            #pragma unroll
            for (int d = 0; d < 4; ++d) {
                const int k = 16 * m + 4 * s + d;
                w[g][m * 4 + d] = (active && k < HID) ? Lg * row[k] : 0.0f;
            }
        }
        wi4[g] = active ? 0.25f * Lg * W_ih[gate] : 0.0f;
        bs4[g] = active ? 0.25f * Lg * (b_ih[gate] + b_hh[gate]) : 0.0f;
    }

    const bool b0   = (s & 1) != 0;
    const bool b1h  = (s & 2) != 0;
    const bool is_g = (s == 2);
    float c = 0.0f;
    __syncthreads();

    // 16 v_fma_f32 with "v"-constrained (ARCH VGPR) weight operands.
    // Interleaved g-major: 4 independent acc chains cover the 4-cyc dep latency.
    // Purpose: make AGPR-homing of the 112 weight floats maximally unprofitable
    // so regalloc keeps them in arch VGPRs (kills the per-use AGPR-read tax
    // that R1/R3/R5 counters show costs ~40% of all busy cycles).
    #define FMA_BLOCK(m)                                                          \
    {   const float4 hv = *(const float4*)(hb + 16 * (m) + 4 * s);                \
        asm("v_fma_f32 %0, %8, %4, %0\n\t"                                        \
            "v_fma_f32 %1, %12, %4, %1\n\t"                                       \
            "v_fma_f32 %2, %16, %4, %2\n\t"                                       \
            "v_fma_f32 %3, %20, %4, %3\n\t"                                       \
            "v_fma_f32 %0, %9, %5, %0\n\t"                                        \
            "v_fma_f32 %1, %13, %5, %1\n\t"                                       \
            "v_fma_f32 %2, %17, %5, %2\n\t"                                       \
            "v_fma_f32 %3, %21, %5, %3\n\t"                                       \
            "v_fma_f32 %0, %10, %6, %0\n\t"                                       \
            "v_fma_f32 %1, %14, %6, %1\n\t"                                       \
            "v_fma_f32 %2, %18, %6, %2\n\t"                                       \
            "v_fma_f32 %3, %22, %6, %3\n\t"                                       \
            "v_fma_f32 %0, %11, %7, %0\n\t"                                       \
            "v_fma_f32 %1, %15, %7, %1\n\t"                                       \
            "v_fma_f32 %2, %19, %7, %2\n\t"                                       \
            "v_fma_f32 %3, %23, %7, %3"                                           \
            : "+v"(acc0), "+v"(acc1), "+v"(acc2), "+v"(acc3)                      \
            : "v"(hv.x), "v"(hv.y), "v"(hv.z), "v"(hv.w),                         \
              "v"(w[0][4*(m)+0]), "v"(w[0][4*(m)+1]),                             \
              "v"(w[0][4*(m)+2]), "v"(w[0][4*(m)+3]),                             \
              "v"(w[1][4*(m)+0]), "v"(w[1][4*(m)+1]),                             \
              "v"(w[1][4*(m)+2]), "v"(w[1][4*(m)+3]),                             \
              "v"(w[2][4*(m)+0]), "v"(w[2][4*(m)+1]),                             \
              "v"(w[2][4*(m)+2]), "v"(w[2][4*(m)+3]),                             \
              "v"(w[3][4*(m)+0]), "v"(w[3][4*(m)+1]),                             \
              "v"(w[3][4*(m)+2]), "v"(w[3][4*(m)+3]));                            \
    }

    for (int t = 0; t < T_STEPS; ++t) {
        const float* hb = h_buf[t & 1];
        const float xt = x_lds[t];

        float acc0 = fmaf(wi4[0], xt, bs4[0]);
        float acc1 = fmaf(wi4[1], xt, bs4[1]);
        float acc2 = fmaf(wi4[2], xt, bs4[2]);
        float acc3 = fmaf(wi4[3], xt, bs4[3]);

        FMA_BLOCK(0)
        FMA_BLOCK(1)
        FMA_BLOCK(2)
        FMA_BLOCK(3)
        FMA_BLOCK(4)
        FMA_BLOCK(5)
        FMA_BLOCK(6)

        // Select-then-butterfly transpose-reduce: lane s ends with the FULL
        // sum of gate s (12 VALU ops).
        float p01  = b0 ? acc1 : acc0;
        float p01s = b0 ? acc0 : acc1;
        float p23  = b0 ? acc3 : acc2;
        float p23s = b0 ? acc2 : acc3;
        p01 += dpp_mov<0xB1>(p01s);
        p23 += dpp_mov<0xB1>(p23s);
        float q  = b1h ? p23 : p01;
        float qs = b1h ? p01 : p23;
        const float tot = q + dpp_mov<0x4E>(qs);

        // lane s activates gate s (i,f,o: sigmoid; g: tanh) — log2e baked in
        const float e   = __builtin_amdgcn_exp2f(-tot);
        const float r   = __builtin_amdgcn_rcpf(1.0f + e);
        const float act = is_g ? fmaf(2.0f, r, -1.0f) : r;

        // redistribute the four activations within the quad (DPP broadcasts)
        const float ig = dpp_mov<0x00>(act);
        const float fg = dpp_mov<0x55>(act);
        const float gg = dpp_mov<0xAA>(act);
        const float og = dpp_mov<0xFF>(act);

        c = fmaf(fg, c, ig * gg);
        const float e2 = __builtin_amdgcn_exp2f(-2.0f * LOG2E * c);
        const float r2 = __builtin_amdgcn_rcpf(1.0f + e2);
        const float h  = og * fmaf(2.0f, r2, -1.0f);

        if (active && s == 0)
            h_buf[(t + 1) & 1][j] = h;
        __syncthreads();
    }
    #undef FMA_BLOCK

    // head: lin = W1 @ h + b1 (64), out = W2 @ lin + b2 (scalar)
    if (tid < 64) {
        const float* rw = W1 + tid * HID;
        const float* hf = h_buf[0];   // T even -> final h in buf 0
        float a = 0.0f;
        for (int k = 0; k < HID; ++k)
            a = fmaf(rw[k], hf[k], a);
        red_lds[tid] = a + b1[tid];
    }
    __syncthreads();
    if (tid == 0) {
        float a = b2[0];
        for (int k = 0; k < 64; ++k)
            a = fmaf(W2[k], red_lds[k], a);
        out[0] = a;
    }
}

extern "C" void kernel_launch(void* const* d_in, const int* in_sizes, int n_in,
                              void* d_out, int out_size, void* d_ws, size_t ws_size,
                              hipStream_t stream) {
    lstm_caviar_kernel<<<1, NTH, 0, stream>>>(
        (const float*)d_in[0],  // input_seq
        (const float*)d_in[1],  // W_ih
        (const float*)d_in[2],  // W_hh
        (const float*)d_in[3],  // b_ih
        (const float*)d_in[4],  // b_hh
        (const float*)d_in[5],  // W1
        (const float*)d_in[6],  // b1
        (const float*)d_in[7],  // W2
        (const float*)d_in[8],  // b2
        (float*)d_out);
}